// Round 2
// baseline (86210.919 us; speedup 1.0000x reference)
//
#include <hip/hip_runtime.h>
#include <hip/hip_cooperative_groups.h>
#include <math.h>

namespace cg = cooperative_groups;

#define B_    32
#define TE    1024
#define TD    512
#define E_    512
#define F_    32
#define K_    31
#define KH    15
#define CHUNK 128
#define NCH   (TE / CHUNK)     // 8 chunks per batch row
#define NBLK  (B_ * NCH)       // 256 blocks = 1 per CU

// ---------------------------------------------------------------------------
// Persistent cooperative kernel: all TD=512 decode steps in one launch.
// Block (b, chunk j) owns t in [j*128, j*128+128) forever:
//   - w_loc (64 KB), conv weights, and the cumulated-alignment window paW
//     (128 + 30 halo) live in LDS across all steps.
//   - per step: conv(paW) -> fT ; 8t x 8u register-tile matmul vs LDS w_loc ;
//     fused tanh-energy epilogue -> eraw chunk ; grid.sync ;
//     max-free row softmax (redundant 1024-value reduce per block) ->
//     e_out chunk + local paW update. eraw double-buffered => 1 sync/step.
// ---------------------------------------------------------------------------
__global__ __launch_bounds__(1024, 4)
void persist_kernel(const float* __restrict__ enc,   // B,TE,E
                    const float* __restrict__ dec,   // B,TD,E
                    const float* __restrict__ cw,    // K,1,F
                    const float* __restrict__ cb,    // F
                    const float* __restrict__ wloc,  // F,U
                    const float* __restrict__ va,    // U
                    const float* __restrict__ ba,    // U
                    float* __restrict__ er0,         // B,TE  raw energies (buf A)
                    float* __restrict__ er1,         // B,TE  raw energies (buf B)
                    float* __restrict__ eout)        // B,TD,TE
{
    __shared__ float Wl[F_ * 512];            // 64 KB, staged once
    __shared__ float fT[F_][CHUNK + 4];       // conv features, +4 pad (bank + f4 align)
    __shared__ float cwS[K_ * F_];            // conv weights
    __shared__ float cbS[F_];
    __shared__ float paW[CHUNK + 2 * KH + 2]; // cumulated alignment window
    __shared__ float red[16];

    const int tid = threadIdx.x;
    const int g   = tid & 63;                 // lane
    const int w   = tid >> 6;                 // wave 0..15
    const int b   = blockIdx.x >> 3;
    const int t0  = (blockIdx.x & 7) * CHUNK;

    // ---- prologue staging (once per launch) ----
    {
        const float4* src = (const float4*)wloc;
        float4* dst = (float4*)Wl;
        #pragma unroll
        for (int i = 0; i < 4; ++i) dst[i * 1024 + tid] = src[i * 1024 + tid];
        if (tid < K_ * F_) cwS[tid] = cw[tid];
        if (tid < F_) cbS[tid] = cb[tid];
        if (tid < CHUNK + 2 * KH + 2) paW[tid] = 0.0f;
    }
    __syncthreads();

    float* ecur = er0;
    float* enxt = er1;

    const float KK  = 2.885390081777927f;     // 2*log2(e)
    const float L2E = 1.4426950408889634f;

    cg::grid_group grid = cg::this_grid();

    for (int s = 0; s < TD; ++s) {
        // ---- location conv: fT[c][t] = cb[c] + sum_k paW[t+k]*cw[k][c] ----
        {
            const int c    = tid & 31;
            const int ts   = tid >> 5;        // 0..31, 4 t each
            const int base = ts * 4;
            float pw[34];
            #pragma unroll
            for (int m = 0; m < 34; ++m) pw[m] = paW[base + m];
            float a0 = cbS[c], a1 = a0, a2 = a0, a3 = a0;
            #pragma unroll
            for (int k = 0; k < K_; ++k) {
                float wv = cwS[k * F_ + c];
                a0 = fmaf(wv, pw[k],     a0);
                a1 = fmaf(wv, pw[k + 1], a1);
                a2 = fmaf(wv, pw[k + 2], a2);
                a3 = fmaf(wv, pw[k + 3], a3);
            }
            fT[c][base]     = a0; fT[c][base + 1] = a1;
            fT[c][base + 2] = a2; fT[c][base + 3] = a3;
        }
        __syncthreads();

        // ---- loc matmul: 8t x 8u per thread, w_loc resident in LDS ----
        float accv[8][8];
        #pragma unroll
        for (int i = 0; i < 8; ++i)
            #pragma unroll
            for (int jj = 0; jj < 8; ++jj) accv[i][jj] = 0.0f;

        const int tb = w * 8;                 // wave's first t (local)
        #pragma unroll 8
        for (int c = 0; c < F_; ++c) {
            float4 fa = *(const float4*)&fT[c][tb];
            float4 fb = *(const float4*)&fT[c][tb + 4];
            float4 w0 = *(const float4*)&Wl[c * 512 + 4 * g];        // u=4g..
            float4 w1 = *(const float4*)&Wl[c * 512 + 256 + 4 * g];  // u=256+4g..
            float fv[8] = {fa.x, fa.y, fa.z, fa.w, fb.x, fb.y, fb.z, fb.w};
            #pragma unroll
            for (int i = 0; i < 8; ++i) {
                accv[i][0] = fmaf(fv[i], w0.x, accv[i][0]);
                accv[i][1] = fmaf(fv[i], w0.y, accv[i][1]);
                accv[i][2] = fmaf(fv[i], w0.z, accv[i][2]);
                accv[i][3] = fmaf(fv[i], w0.w, accv[i][3]);
                accv[i][4] = fmaf(fv[i], w1.x, accv[i][4]);
                accv[i][5] = fmaf(fv[i], w1.y, accv[i][5]);
                accv[i][6] = fmaf(fv[i], w1.z, accv[i][6]);
                accv[i][7] = fmaf(fv[i], w1.w, accv[i][7]);
            }
        }

        // ---- energy epilogue: tanh + dot(v_a) + wave-reduce over u ----
        {
            const float* qrow = dec + ((size_t)b * TD + s) * E_;
            float4 q0  = ((const float4*)qrow)[g];
            float4 q1  = ((const float4*)qrow)[64 + g];
            float4 bb0 = ((const float4*)ba)[g];
            float4 bb1 = ((const float4*)ba)[64 + g];
            float4 vv0 = ((const float4*)va)[g];
            float4 vv1 = ((const float4*)va)[64 + g];
            float qB[8] = {q0.x + bb0.x, q0.y + bb0.y, q0.z + bb0.z, q0.w + bb0.w,
                           q1.x + bb1.x, q1.y + bb1.y, q1.z + bb1.z, q1.w + bb1.w};
            float Vv[8] = {vv0.x, vv0.y, vv0.z, vv0.w, vv1.x, vv1.y, vv1.z, vv1.w};

            #pragma unroll
            for (int i = 0; i < 8; ++i) {
                const int t = t0 + tb + i;
                const float4* er = (const float4*)(enc + ((size_t)b * TE + t) * E_);
                float4 e0 = er[g];
                float4 e1 = er[64 + g];
                float ev[8] = {e0.x, e0.y, e0.z, e0.w, e1.x, e1.y, e1.z, e1.w};
                float ssum = 0.0f;
                #pragma unroll
                for (int jj = 0; jj < 8; ++jj) {
                    float x  = accv[i][jj] + ev[jj] + qB[jj];
                    float r  = __builtin_amdgcn_exp2f(x * KK);     // e^{2x}
                    float rc = __builtin_amdgcn_rcpf(r + 1.0f);
                    float th = fmaf(-2.0f, rc, 1.0f);              // tanh(x)
                    ssum = fmaf(Vv[jj], th, ssum);
                }
                #pragma unroll
                for (int off = 32; off; off >>= 1) ssum += __shfl_xor(ssum, off);
                if (g == 0) ecur[(size_t)b * TE + t] = ssum;
            }
        }

        __threadfence();
        grid.sync();

        // ---- max-free softmax over the full row + cumulate into paW ----
        // |eraw| <= sum|v_a| <= 25.6  =>  exp2 exponent <= 37, no overflow.
        float myv = ecur[(size_t)b * TE + tid];
        float p   = __builtin_amdgcn_exp2f(myv * L2E);
        float ssum = p;
        #pragma unroll
        for (int off = 32; off; off >>= 1) ssum += __shfl_xor(ssum, off);
        if (g == 0) red[w] = ssum;
        __syncthreads();
        float S = 0.0f;
        #pragma unroll
        for (int k = 0; k < 16; ++k) S += red[k];
        float inv = 1.0f / S;

        if (tid >= t0 && tid < t0 + CHUNK)
            eout[((size_t)b * TD + s) * TE + tid] = p * inv;

        // local (redundant, deterministic) halo update of cumulated alignment
        if (tid < CHUNK + 2 * KH) {
            const int t = t0 - KH + tid;
            if (t >= 0 && t < TE) {
                float pv = __builtin_amdgcn_exp2f(ecur[(size_t)b * TE + t] * L2E) * inv;
                paW[tid] += pv;
            }
        }
        __syncthreads();   // paW/red/fT reuse safe for next step

        float* tmp = ecur; ecur = enxt; enxt = tmp;
    }
}

// ---------------------------------------------------------------------------
// Context matmul: c[b,d,e] = sum_t eo[b,d,t] * enc[b,t,e]  (unchanged)
// ---------------------------------------------------------------------------
__global__ __launch_bounds__(256)
void context_kernel(const float* __restrict__ eo,   // B,TD,TE
                    const float* __restrict__ enc,  // B,TE,E
                    float* __restrict__ cout)       // B,TD,E
{
    __shared__ float eoT[64][36];
    const int b = blockIdx.y, d0 = blockIdx.x * 32, tid = threadIdx.x;

    float2 acc[32];
    #pragma unroll
    for (int d = 0; d < 32; ++d) { acc[d].x = 0.0f; acc[d].y = 0.0f; }

    for (int tc = 0; tc < TE / 64; ++tc) {
        __syncthreads();
        #pragma unroll
        for (int r = 0; r < 8; ++r) {
            int lin = r * 256 + tid;
            int d = lin >> 6, t = lin & 63;
            eoT[t][d] = eo[((size_t)b * TD + d0 + d) * TE + tc * 64 + t];
        }
        __syncthreads();
        #pragma unroll 4
        for (int t = 0; t < 64; ++t) {
            float2 ev = *(const float2*)&enc[((size_t)b * TE + tc * 64 + t) * E_ + 2 * tid];
            #pragma unroll
            for (int dq = 0; dq < 8; ++dq) {
                float4 wv = *(const float4*)&eoT[t][dq * 4];
                acc[dq * 4 + 0].x += wv.x * ev.x; acc[dq * 4 + 0].y += wv.x * ev.y;
                acc[dq * 4 + 1].x += wv.y * ev.x; acc[dq * 4 + 1].y += wv.y * ev.y;
                acc[dq * 4 + 2].x += wv.z * ev.x; acc[dq * 4 + 2].y += wv.z * ev.y;
                acc[dq * 4 + 3].x += wv.w * ev.x; acc[dq * 4 + 3].y += wv.w * ev.y;
            }
        }
    }
    #pragma unroll
    for (int d = 0; d < 32; ++d)
        *(float2*)&cout[((size_t)b * TD + d0 + d) * E_ + 2 * tid] = acc[d];
}

// ---------------------------------------------------------------------------
extern "C" void kernel_launch(void* const* d_in, const int* in_sizes, int n_in,
                              void* d_out, int out_size, void* d_ws, size_t ws_size,
                              hipStream_t stream) {
    const float* enc  = (const float*)d_in[0];
    const float* dec  = (const float*)d_in[1];
    const float* cw   = (const float*)d_in[2];
    const float* cb   = (const float*)d_in[3];
    const float* wloc = (const float*)d_in[4];
    const float* va   = (const float*)d_in[5];
    const float* ba   = (const float*)d_in[6];

    float* c_out = (float*)d_out;                          // B*TD*E
    float* e_out = (float*)d_out + (size_t)B_ * TD * E_;   // B*TD*TE

    float* er0 = (float*)d_ws;                             // B*TE
    float* er1 = er0 + (size_t)B_ * TE;                    // B*TE

    void* args[] = {(void*)&enc, (void*)&dec, (void*)&cw, (void*)&cb,
                    (void*)&wloc, (void*)&va, (void*)&ba,
                    (void*)&er0, (void*)&er1, (void*)&e_out};
    hipLaunchCooperativeKernel((void*)persist_kernel, dim3(NBLK), dim3(1024),
                               args, 0, stream);

    context_kernel<<<dim3(TD / 32, B_), 256, 0, stream>>>(e_out, enc, c_out);
}

// Round 4
// 13260.168 us; speedup vs baseline: 6.5015x; 6.5015x over previous
//
#include <hip/hip_runtime.h>
#include <math.h>

#define B_    32
#define TE    1024
#define TD    512
#define E_    512
#define F_    32
#define K_    31
#define KH    15
#define CHUNK 64
#define NCH   (TE / CHUNK)        // 16 chunks per batch row
#define NBLK  (B_ * NCH)          // 512 blocks (2 per CU)

// ---------------------------------------------------------------------------
// One launch per decode step s. Block (b, chunk) owns t in [chunk*64, +64).
// Phase 1: finish step s-1 softmax (normalize praw by sum of partials),
//          write e_out[s-1], update cumulated alignment (double-buffered),
//          build local paW window (64 + 2*15 halo) in LDS.
// Phase 2: location conv paW -> fT[32][64].
// Phase 3: 8t x 8u register-tile matmul vs LDS w_loc, fused tanh-energy,
//          write unnormalized p = exp(e) and per-chunk partial sum.
// All cross-block dataflow crosses the kernel boundary -> no fences needed.
// ---------------------------------------------------------------------------
__global__ __launch_bounds__(512, 4)
void step_kernel(const float* __restrict__ enc,   // B,TE,E
                 const float* __restrict__ dec,   // B,TD,E
                 const float* __restrict__ cw,    // K,1,F
                 const float* __restrict__ cb,    // F
                 const float* __restrict__ wloc,  // F,U
                 const float* __restrict__ va,    // U
                 const float* __restrict__ ba,    // U
                 const float* __restrict__ prA,   // B,TE   exp(e) of step s-1
                 const float* __restrict__ PsA,   // B,NCH  partial sums, s-1
                 const float* __restrict__ paA,   // B,TE   cum align thru s-2
                 float* __restrict__ prB,         // B,TE   exp(e) of step s
                 float* __restrict__ PsB,         // B,NCH  partial sums, s
                 float* __restrict__ paB,         // B,TE   cum align thru s-1
                 float* __restrict__ eout,        // B,TD,TE
                 int step)
{
    __shared__ float Wl[F_ * 512];            // 64 KB w_loc
    __shared__ float fT[F_][CHUNK + 4];       // conv features [c][t], stride 68
    __shared__ float cwS[K_ * F_];
    __shared__ float cbS[F_];
    __shared__ float paW[CHUNK + 2 * KH + 2]; // 96
    __shared__ float red[16];

    const int tid   = threadIdx.x;
    const int g     = tid & 63;
    const int w     = tid >> 6;               // wave 0..7
    const int b     = blockIdx.x >> 4;
    const int chunk = blockIdx.x & 15;
    const int t0    = chunk * CHUNK;
    const float L2E = 1.4426950408889634f;
    const float KK  = 2.885390081777927f;     // 2*log2(e)

    // ---- stage w_loc + conv weights (per launch) ----
    {
        const float4* src = (const float4*)wloc;
        float4* dst = (float4*)Wl;
        #pragma unroll
        for (int i = 0; i < 8; ++i) dst[i * 512 + tid] = src[i * 512 + tid];
        // BUGFIX R3: K_*F_ = 992 > blockDim 512 -> must stride, not mask.
        for (int i = tid; i < K_ * F_; i += 512) cwS[i] = cw[i];
        if (tid < F_) cbS[tid] = cb[tid];
    }
    if (tid < NCH && step > 0) red[tid] = PsA[b * NCH + tid];
    __syncthreads();

    // ---- phase 1: finish previous softmax, build paW ----
    if (step == 0) {
        if (tid < CHUNK + 2 * KH + 2) paW[tid] = 0.0f;
        if (tid < CHUNK) paB[(size_t)b * TE + t0 + tid] = 0.0f;
    } else {
        float S = 0.0f;
        #pragma unroll
        for (int k = 0; k < NCH; ++k) S += red[k];
        float inv = 1.0f / S;
        if (tid < CHUNK + 2 * KH) {
            int t = t0 - KH + tid;
            float v = 0.0f;
            if (t >= 0 && t < TE)
                v = paA[(size_t)b * TE + t] + prA[(size_t)b * TE + t] * inv;
            paW[tid] = v;
        }
        if (tid < 2) paW[CHUNK + 2 * KH + tid] = 0.0f;
        if (tid < CHUNK) {
            int t = t0 + tid;
            float pn = prA[(size_t)b * TE + t] * inv;
            eout[((size_t)b * TD + (step - 1)) * TE + t] = pn;
            paB[(size_t)b * TE + t] = paA[(size_t)b * TE + t] + pn;
        }
    }
    __syncthreads();

    // ---- phase 2: location conv: fT[c][t] = cb[c] + sum_k paW[t+k]*cw[k][c]
    {
        const int c    = tid & 31;
        const int ts   = tid >> 5;            // 0..15, 4 t each
        const int base = ts * 4;
        float pw[34];
        #pragma unroll
        for (int m = 0; m < 34; ++m) pw[m] = paW[base + m];
        float a0 = cbS[c], a1 = a0, a2 = a0, a3 = a0;
        #pragma unroll
        for (int k = 0; k < K_; ++k) {
            float wv = cwS[k * F_ + c];
            a0 = fmaf(wv, pw[k],     a0);
            a1 = fmaf(wv, pw[k + 1], a1);
            a2 = fmaf(wv, pw[k + 2], a2);
            a3 = fmaf(wv, pw[k + 3], a3);
        }
        fT[c][base]     = a0; fT[c][base + 1] = a1;
        fT[c][base + 2] = a2; fT[c][base + 3] = a3;
    }
    __syncthreads();

    // ---- phase 3: matmul 8t x 8u + fused energy ----
    float accv[8][8];
    #pragma unroll
    for (int i = 0; i < 8; ++i)
        #pragma unroll
        for (int j = 0; j < 8; ++j) accv[i][j] = 0.0f;

    const int tb = w * 8;
    #pragma unroll 8
    for (int c = 0; c < F_; ++c) {
        float4 fa = *(const float4*)&fT[c][tb];
        float4 fb = *(const float4*)&fT[c][tb + 4];
        float4 w0 = *(const float4*)&Wl[c * 512 + 4 * g];        // u=4g..
        float4 w1 = *(const float4*)&Wl[c * 512 + 256 + 4 * g];  // u=256+4g..
        float fv[8] = {fa.x, fa.y, fa.z, fa.w, fb.x, fb.y, fb.z, fb.w};
        #pragma unroll
        for (int i = 0; i < 8; ++i) {
            accv[i][0] = fmaf(fv[i], w0.x, accv[i][0]);
            accv[i][1] = fmaf(fv[i], w0.y, accv[i][1]);
            accv[i][2] = fmaf(fv[i], w0.z, accv[i][2]);
            accv[i][3] = fmaf(fv[i], w0.w, accv[i][3]);
            accv[i][4] = fmaf(fv[i], w1.x, accv[i][4]);
            accv[i][5] = fmaf(fv[i], w1.y, accv[i][5]);
            accv[i][6] = fmaf(fv[i], w1.z, accv[i][6]);
            accv[i][7] = fmaf(fv[i], w1.w, accv[i][7]);
        }
    }

    float sp = 0.0f;                          // partial sum of exp(e), per wave
    {
        const float* qrow = dec + ((size_t)b * TD + step) * E_;
        float4 q0  = ((const float4*)qrow)[g];
        float4 q1  = ((const float4*)qrow)[64 + g];
        float4 bb0 = ((const float4*)ba)[g];
        float4 bb1 = ((const float4*)ba)[64 + g];
        float4 vv0 = ((const float4*)va)[g];
        float4 vv1 = ((const float4*)va)[64 + g];
        float qB[8] = {q0.x + bb0.x, q0.y + bb0.y, q0.z + bb0.z, q0.w + bb0.w,
                       q1.x + bb1.x, q1.y + bb1.y, q1.z + bb1.z, q1.w + bb1.w};
        float Vv[8] = {vv0.x, vv0.y, vv0.z, vv0.w, vv1.x, vv1.y, vv1.z, vv1.w};

        #pragma unroll
        for (int i = 0; i < 8; ++i) {
            const int t = t0 + tb + i;
            const float4* er = (const float4*)(enc + ((size_t)b * TE + t) * E_);
            float4 e0 = er[g];
            float4 e1 = er[64 + g];
            float ev[8] = {e0.x, e0.y, e0.z, e0.w, e1.x, e1.y, e1.z, e1.w};
            float ssum = 0.0f;
            #pragma unroll
            for (int jj = 0; jj < 8; ++jj) {
                float x  = accv[i][jj] + ev[jj] + qB[jj];
                float r  = __builtin_amdgcn_exp2f(x * KK);       // e^{2x}
                float rc = __builtin_amdgcn_rcpf(r + 1.0f);
                float th = fmaf(-2.0f, rc, 1.0f);                // tanh(x)
                ssum = fmaf(Vv[jj], th, ssum);
            }
            #pragma unroll
            for (int off = 32; off; off >>= 1) ssum += __shfl_xor(ssum, off);
            // max-free softmax: |e| <= sum|v_a| <= 12.8 -> exp safe in fp32
            float p = __builtin_amdgcn_exp2f(ssum * L2E);
            sp += p;
            if (g == 0) prB[(size_t)b * TE + t] = p;
        }
    }
    __syncthreads();                          // red[] free for reuse
    if (g == 0) red[w] = sp;
    __syncthreads();
    if (tid == 0) {
        float s8 = 0.0f;
        #pragma unroll
        for (int k = 0; k < 8; ++k) s8 += red[k];
        PsB[b * NCH + chunk] = s8;
    }
}

// ---------------------------------------------------------------------------
// Finish softmax of the last step (TD-1): e_out only.
// ---------------------------------------------------------------------------
__global__ __launch_bounds__(256)
void finish_kernel(const float* __restrict__ pr,   // B,TE
                   const float* __restrict__ Ps,   // B,NCH
                   float* __restrict__ eout)
{
    const int b = blockIdx.x, tid = threadIdx.x;
    float S = 0.0f;
    #pragma unroll
    for (int k = 0; k < NCH; ++k) S += Ps[b * NCH + k];
    float inv = 1.0f / S;
    float4 p = ((const float4*)(pr + (size_t)b * TE))[tid];
    p.x *= inv; p.y *= inv; p.z *= inv; p.w *= inv;
    *(float4*)&eout[((size_t)b * TD + (TD - 1)) * TE + tid * 4] = p;
}

// ---------------------------------------------------------------------------
// Context matmul: c[b,d,e] = sum_t eo[b,d,t] * enc[b,t,e]
// ---------------------------------------------------------------------------
__global__ __launch_bounds__(256)
void context_kernel(const float* __restrict__ eo,   // B,TD,TE
                    const float* __restrict__ enc,  // B,TE,E
                    float* __restrict__ cout)       // B,TD,E
{
    __shared__ float eoT[64][36];
    const int b = blockIdx.y, d0 = blockIdx.x * 32, tid = threadIdx.x;

    float2 acc[32];
    #pragma unroll
    for (int d = 0; d < 32; ++d) { acc[d].x = 0.0f; acc[d].y = 0.0f; }

    for (int tc = 0; tc < TE / 64; ++tc) {
        __syncthreads();
        #pragma unroll
        for (int r = 0; r < 8; ++r) {
            int lin = r * 256 + tid;
            int d = lin >> 6, t = lin & 63;
            eoT[t][d] = eo[((size_t)b * TD + d0 + d) * TE + tc * 64 + t];
        }
        __syncthreads();
        #pragma unroll 4
        for (int t = 0; t < 64; ++t) {
            float2 ev = *(const float2*)&enc[((size_t)b * TE + tc * 64 + t) * E_ + 2 * tid];
            #pragma unroll
            for (int dq = 0; dq < 8; ++dq) {
                float4 wv = *(const float4*)&eoT[t][dq * 4];
                acc[dq * 4 + 0].x += wv.x * ev.x; acc[dq * 4 + 0].y += wv.x * ev.y;
                acc[dq * 4 + 1].x += wv.y * ev.x; acc[dq * 4 + 1].y += wv.y * ev.y;
                acc[dq * 4 + 2].x += wv.z * ev.x; acc[dq * 4 + 2].y += wv.z * ev.y;
                acc[dq * 4 + 3].x += wv.w * ev.x; acc[dq * 4 + 3].y += wv.w * ev.y;
            }
        }
    }
    #pragma unroll
    for (int d = 0; d < 32; ++d)
        *(float2*)&cout[((size_t)b * TD + d0 + d) * E_ + 2 * tid] = acc[d];
}

// ---------------------------------------------------------------------------
extern "C" void kernel_launch(void* const* d_in, const int* in_sizes, int n_in,
                              void* d_out, int out_size, void* d_ws, size_t ws_size,
                              hipStream_t stream) {
    const float* enc  = (const float*)d_in[0];
    const float* dec  = (const float*)d_in[1];
    const float* cw   = (const float*)d_in[2];
    const float* cb   = (const float*)d_in[3];
    const float* wloc = (const float*)d_in[4];
    const float* va   = (const float*)d_in[5];
    const float* ba   = (const float*)d_in[6];

    float* c_out = (float*)d_out;                          // B*TD*E
    float* e_out = (float*)d_out + (size_t)B_ * TD * E_;   // B*TD*TE

    float* ws = (float*)d_ws;
    float* pr[2] = {ws,                 ws + (size_t)B_ * TE};
    float* Ps[2] = {ws + 2 * (size_t)B_ * TE,
                    ws + 2 * (size_t)B_ * TE + B_ * NCH};
    float* pa[2] = {ws + 2 * (size_t)B_ * TE + 2 * B_ * NCH,
                    ws + 3 * (size_t)B_ * TE + 2 * B_ * NCH};

    // launch s reads X[s&1], writes X[(s+1)&1]; s=0 reads nothing (first).
    for (int s = 0; s < TD; ++s) {
        int ra = s & 1, wb = (s + 1) & 1;
        step_kernel<<<NBLK, 512, 0, stream>>>(
            enc, dec, cw, cb, wloc, va, ba,
            pr[ra], Ps[ra], pa[ra],
            pr[wb], Ps[wb], pa[wb],
            e_out, s);
    }
    // last step's softmax (written into X[TD&1] == X[0])
    finish_kernel<<<B_, 256, 0, stream>>>(pr[0], Ps[0], e_out);
    context_kernel<<<dim3(TD / 32, B_), 256, 0, stream>>>(e_out, enc, c_out);
}

// Round 6
// 9456.214 us; speedup vs baseline: 9.1169x; 1.4023x over previous
//
#include <hip/hip_runtime.h>
#include <math.h>

#define B_    32
#define TE    1024
#define TD    512
#define E_    512
#define F_    32
#define K_    31
#define KH    15
#define CHUNK 64
#define NCH   (TE / CHUNK)        // 16 chunks per batch row
#define NBLK  (B_ * NCH)          // 512 blocks (2 per CU)

typedef __attribute__((ext_vector_type(8))) short short8;
typedef __attribute__((ext_vector_type(4))) float f32x4;

__device__ __forceinline__ unsigned short f2bf(float x) {   // RNE f32->bf16
    unsigned u = __float_as_uint(x);
    unsigned r = (u + 0x7fffu + ((u >> 16) & 1u)) >> 16;
    return (unsigned short)r;
}
__device__ __forceinline__ float bf2f(unsigned short h) {
    return __uint_as_float(((unsigned)h) << 16);
}

// ---------------------------------------------------------------------------
// Prologue (once per call): w_loc (F,U row-major) -> transposed bf16 hi/lo
// [u][c] for direct B-fragment loads.  hi=RNE(x), lo=RNE(x-hi): 3-term MFMA
// product fh*Wh+fh*Wl+fl*Wh has rel err ~2^-17.
// ---------------------------------------------------------------------------
__global__ void prep_kernel(const float* __restrict__ wloc,
                            unsigned short* __restrict__ WTh,
                            unsigned short* __restrict__ WTl)
{
    const int u = threadIdx.x;                 // 512 threads
    #pragma unroll
    for (int c = 0; c < F_; ++c) {
        float x = wloc[c * 512 + u];
        unsigned short h = f2bf(x);
        float lo = x - bf2f(h);
        WTh[u * F_ + c] = h;
        WTl[u * F_ + c] = f2bf(lo);
    }
}

// ---------------------------------------------------------------------------
// One launch per decode step s. Block (b, chunk) owns t in [chunk*64, +64).
// Phase 1: finish step s-1 softmax, update cum-align (double-buffered), build
//          local paW window in LDS.
// Phase 2: location conv paW -> fT (bf16 hi/lo, A-operand layout [t][c]).
// Phase 3: split-bf16 MFMA. Wave w owns u in [64w, 64w+64) (4 u-tiles of 16)
//          *** R6 fix: R5 only covered u<256 (2 u-tiles/wave) — half of U ***
//          and all 64 t (4 t-tiles). Per t-tile: 12 MFMA then immediate
//          epilogue (acc dies -> low VGPR). 16-lane reduce gives per-wave
//          partial over its 64 u; 8 wave-partials summed via LDS.
// ---------------------------------------------------------------------------
__global__ __launch_bounds__(512, 4)
void step_kernel(const float* __restrict__ enc,   // B,TE,E
                 const float* __restrict__ dec,   // B,TD,E
                 const float* __restrict__ cw,    // K,1,F
                 const float* __restrict__ cb,    // F
                 const unsigned short* __restrict__ WTh, // U,F bf16 hi
                 const unsigned short* __restrict__ WTl, // U,F bf16 lo
                 const float* __restrict__ va,    // U
                 const float* __restrict__ ba,    // U
                 const float* __restrict__ prA,   // B,TE   exp(e) of s-1
                 const float* __restrict__ PsA,   // B,NCH  partial sums, s-1
                 const float* __restrict__ paA,   // B,TE   cum align thru s-2
                 float* __restrict__ prB,         // B,TE   exp(e) of s
                 float* __restrict__ PsB,         // B,NCH  partial sums, s
                 float* __restrict__ paB,         // B,TE   cum align thru s-1
                 float* __restrict__ eout,        // B,TD,TE
                 int step)
{
    __shared__ __align__(16) unsigned short fThS[CHUNK * F_]; // A-frag hi [t][c]
    __shared__ __align__(16) unsigned short fTlS[CHUNK * F_]; // A-frag lo
    __shared__ float cwS[K_ * F_];
    __shared__ float cbS[F_];
    __shared__ float paW[CHUNK + 2 * KH + 4];                 // 98
    __shared__ float red[NCH];
    __shared__ float redT[CHUNK][9];                          // [t][wave], pad

    const int tid   = threadIdx.x;
    const int g     = tid & 63;
    const int w     = tid >> 6;               // wave 0..7
    const int q     = g >> 4;                 // quad 0..3 (k-chunk / row-group)
    const int n16   = g & 15;
    const int b     = blockIdx.x >> 4;
    const int chunk = blockIdx.x & 15;
    const int t0    = chunk * CHUNK;
    const float L2E = 1.4426950408889634f;
    const float KK  = 2.885390081777927f;     // 2*log2(e)

    // ---- B-fragments: wave w covers u in [64w, 64w+64), 4 u-tiles ----
    // B layout: lane holds B[k=q*8+j][n=n16] -> row u=64w+16*ut+n16 of WTh.
    short8 bh[4], bl[4];
    int uu[4];
    #pragma unroll
    for (int ut = 0; ut < 4; ++ut) {
        uu[ut] = w * 64 + ut * 16 + n16;
        bh[ut] = ((const short8*)WTh)[uu[ut] * 4 + q];
        bl[ut] = ((const short8*)WTl)[uu[ut] * 4 + q];
    }

    // ---- stage conv weights ----
    for (int i = tid; i < K_ * F_; i += 512) cwS[i] = cw[i];
    if (tid < F_) cbS[tid] = cb[tid];
    if (tid < NCH && step > 0) red[tid] = PsA[b * NCH + tid];
    __syncthreads();

    // ---- phase 1: finish previous softmax, build paW ----
    if (step == 0) {
        if (tid < CHUNK + 2 * KH + 4) paW[tid] = 0.0f;
        if (tid < CHUNK) paB[(size_t)b * TE + t0 + tid] = 0.0f;
    } else {
        float S = 0.0f;
        #pragma unroll
        for (int k = 0; k < NCH; ++k) S += red[k];
        float inv = 1.0f / S;
        if (tid < CHUNK + 2 * KH) {
            int t = t0 - KH + tid;
            float v = 0.0f;
            if (t >= 0 && t < TE)
                v = paA[(size_t)b * TE + t] + prA[(size_t)b * TE + t] * inv;
            paW[tid] = v;
        }
        if (tid < 4) paW[CHUNK + 2 * KH + tid] = 0.0f;
        if (tid < CHUNK) {
            int t = t0 + tid;
            float pn = prA[(size_t)b * TE + t] * inv;
            eout[((size_t)b * TD + (step - 1)) * TE + t] = pn;
            paB[(size_t)b * TE + t] = paA[(size_t)b * TE + t] + pn;
        }
    }
    __syncthreads();

    // ---- phase 2: conv -> fT bf16 hi/lo in A-operand layout [t][c] ----
    {
        const int c    = tid & 31;
        const int ts   = tid >> 5;            // 0..15, 4 t each
        const int base = ts * 4;
        float pw[34];
        #pragma unroll
        for (int m = 0; m < 34; ++m) pw[m] = paW[base + m];
        float a0 = cbS[c], a1 = a0, a2 = a0, a3 = a0;
        #pragma unroll
        for (int k = 0; k < K_; ++k) {
            float wv = cwS[k * F_ + c];
            a0 = fmaf(wv, pw[k],     a0);
            a1 = fmaf(wv, pw[k + 1], a1);
            a2 = fmaf(wv, pw[k + 2], a2);
            a3 = fmaf(wv, pw[k + 3], a3);
        }
        float av[4] = {a0, a1, a2, a3};
        #pragma unroll
        for (int i = 0; i < 4; ++i) {
            unsigned short h = f2bf(av[i]);
            fThS[(base + i) * F_ + c] = h;
            fTlS[(base + i) * F_ + c] = f2bf(av[i] - bf2f(h));
        }
    }
    __syncthreads();

    // ---- phase 3: MFMA matmul + fused epilogue, one t-tile at a time ----
    const float* qrow = dec + ((size_t)b * TD + step) * E_;
    float qb[4], vv[4];
    #pragma unroll
    for (int ut = 0; ut < 4; ++ut) {
        qb[ut] = qrow[uu[ut]] + ba[uu[ut]];
        vv[ut] = va[uu[ut]];
    }

    const short8* AH = (const short8*)fThS;
    const short8* AL = (const short8*)fTlS;

    #pragma unroll
    for (int tt = 0; tt < 4; ++tt) {
        short8 ah = AH[(tt * 16 + n16) * 4 + q];   // A[m=n16][k=q*8+j]
        short8 al = AL[(tt * 16 + n16) * 4 + q];
        f32x4 acc[4];
        #pragma unroll
        for (int ut = 0; ut < 4; ++ut) {
            acc[ut] = (f32x4){0, 0, 0, 0};
            acc[ut] = __builtin_amdgcn_mfma_f32_16x16x32_bf16(ah, bh[ut], acc[ut], 0, 0, 0);
            acc[ut] = __builtin_amdgcn_mfma_f32_16x16x32_bf16(al, bh[ut], acc[ut], 0, 0, 0);
            acc[ut] = __builtin_amdgcn_mfma_f32_16x16x32_bf16(ah, bl[ut], acc[ut], 0, 0, 0);
        }
        // epilogue: D row = tt*16 + q*4 + r, col = uu[ut]
        #pragma unroll
        for (int r = 0; r < 4; ++r) {
            const int tl = tt * 16 + q * 4 + r;
            const float* erow = enc + ((size_t)b * TE + t0 + tl) * E_;
            float s = 0.0f;
            #pragma unroll
            for (int ut = 0; ut < 4; ++ut) {
                float x  = acc[ut][r] + erow[uu[ut]] + qb[ut];
                float rr = __builtin_amdgcn_exp2f(x * KK);       // e^{2x}
                float th = fmaf(-2.0f, __builtin_amdgcn_rcpf(rr + 1.0f), 1.0f);
                s = fmaf(vv[ut], th, s);
            }
            // reduce over the 16 n16-lanes holding this t (all 64 u of wave)
            s += __shfl_xor(s, 1);
            s += __shfl_xor(s, 2);
            s += __shfl_xor(s, 4);
            s += __shfl_xor(s, 8);
            if (n16 == 0) redT[tl][w] = s;
        }
    }
    __syncthreads();

    // ---- final: sum 8 wave-partials per t, exp, write p + chunk sum ----
    if (tid < CHUNK) {
        float e = 0.0f;
        #pragma unroll
        for (int k = 0; k < 8; ++k) e += redT[tid][k];
        // max-free softmax: |e| <= sum|v_a| <= 25.6 -> exp2 arg <= 37, safe
        float p = __builtin_amdgcn_exp2f(e * L2E);
        prB[(size_t)b * TE + t0 + tid] = p;
        float sp = p;
        #pragma unroll
        for (int off = 32; off; off >>= 1) sp += __shfl_xor(sp, off);
        if (tid == 0) PsB[b * NCH + chunk] = sp;
    }
}

// ---------------------------------------------------------------------------
// Finish softmax of the last step (TD-1): e_out only.
// ---------------------------------------------------------------------------
__global__ __launch_bounds__(256)
void finish_kernel(const float* __restrict__ pr,   // B,TE
                   const float* __restrict__ Ps,   // B,NCH
                   float* __restrict__ eout)
{
    const int b = blockIdx.x, tid = threadIdx.x;
    float S = 0.0f;
    #pragma unroll
    for (int k = 0; k < NCH; ++k) S += Ps[b * NCH + k];
    float inv = 1.0f / S;
    float4 p = ((const float4*)(pr + (size_t)b * TE))[tid];
    p.x *= inv; p.y *= inv; p.z *= inv; p.w *= inv;
    *(float4*)&eout[((size_t)b * TD + (TD - 1)) * TE + tid * 4] = p;
}

// ---------------------------------------------------------------------------
// Context matmul: c[b,d,e] = sum_t eo[b,d,t] * enc[b,t,e]
// ---------------------------------------------------------------------------
__global__ __launch_bounds__(256)
void context_kernel(const float* __restrict__ eo,   // B,TD,TE
                    const float* __restrict__ enc,  // B,TE,E
                    float* __restrict__ cout)       // B,TD,E
{
    __shared__ float eoT[64][36];
    const int b = blockIdx.y, d0 = blockIdx.x * 32, tid = threadIdx.x;

    float2 acc[32];
    #pragma unroll
    for (int d = 0; d < 32; ++d) { acc[d].x = 0.0f; acc[d].y = 0.0f; }

    for (int tc = 0; tc < TE / 64; ++tc) {
        __syncthreads();
        #pragma unroll
        for (int r = 0; r < 8; ++r) {
            int lin = r * 256 + tid;
            int d = lin >> 6, t = lin & 63;
            eoT[t][d] = eo[((size_t)b * TD + d0 + d) * TE + tc * 64 + t];
        }
        __syncthreads();
        #pragma unroll 4
        for (int t = 0; t < 64; ++t) {
            float2 ev = *(const float2*)&enc[((size_t)b * TE + tc * 64 + t) * E_ + 2 * tid];
            #pragma unroll
            for (int dq = 0; dq < 8; ++dq) {
                float4 wv = *(const float4*)&eoT[t][dq * 4];
                acc[dq * 4 + 0].x += wv.x * ev.x; acc[dq * 4 + 0].y += wv.x * ev.y;
                acc[dq * 4 + 1].x += wv.y * ev.x; acc[dq * 4 + 1].y += wv.y * ev.y;
                acc[dq * 4 + 2].x += wv.z * ev.x; acc[dq * 4 + 2].y += wv.z * ev.y;
                acc[dq * 4 + 3].x += wv.w * ev.x; acc[dq * 4 + 3].y += wv.w * ev.y;
            }
        }
    }
    #pragma unroll
    for (int d = 0; d < 32; ++d)
        *(float2*)&cout[((size_t)b * TD + d0 + d) * E_ + 2 * tid] = acc[d];
}

// ---------------------------------------------------------------------------
extern "C" void kernel_launch(void* const* d_in, const int* in_sizes, int n_in,
                              void* d_out, int out_size, void* d_ws, size_t ws_size,
                              hipStream_t stream) {
    const float* enc  = (const float*)d_in[0];
    const float* dec  = (const float*)d_in[1];
    const float* cw   = (const float*)d_in[2];
    const float* cb   = (const float*)d_in[3];
    const float* wloc = (const float*)d_in[4];
    const float* va   = (const float*)d_in[5];
    const float* ba   = (const float*)d_in[6];

    float* c_out = (float*)d_out;                          // B*TD*E
    float* e_out = (float*)d_out + (size_t)B_ * TD * E_;   // B*TD*TE

    float* ws = (float*)d_ws;
    float* pr[2] = {ws,                 ws + (size_t)B_ * TE};
    float* Ps[2] = {ws + 2 * (size_t)B_ * TE,
                    ws + 2 * (size_t)B_ * TE + B_ * NCH};
    float* pa[2] = {ws + 2 * (size_t)B_ * TE + 2 * B_ * NCH,
                    ws + 3 * (size_t)B_ * TE + 2 * B_ * NCH};
    unsigned short* WTh = (unsigned short*)(ws + 4 * (size_t)B_ * TE + 2 * B_ * NCH);
    unsigned short* WTl = WTh + 512 * F_;

    prep_kernel<<<1, 512, 0, stream>>>(wloc, WTh, WTl);

    // launch s reads X[s&1], writes X[(s+1)&1]; s=0 reads nothing (first).
    for (int s = 0; s < TD; ++s) {
        int ra = s & 1, wb = (s + 1) & 1;
        step_kernel<<<NBLK, 512, 0, stream>>>(
            enc, dec, cw, cb, WTh, WTl, va, ba,
            pr[ra], Ps[ra], pa[ra],
            pr[wb], Ps[wb], pa[wb],
            e_out, s);
    }
    // last step's softmax (written into X[TD&1] == X[0])
    finish_kernel<<<B_, 256, 0, stream>>>(pr[0], Ps[0], e_out);
    context_kernel<<<dim3(TD / 32, B_), 256, 0, stream>>>(e_out, enc, c_out);
}